// Round 7
// baseline (192.836 us; speedup 1.0000x reference)
//
#include <hip/hip_runtime.h>
#include <climits>

#define B    8192
#define D    256
#define TOT  16384
#define GS   16
#define NC   (GS * GS * GS)   // 4096 grid cells
#define NB   4096             // value buckets for rank
#define RPB  128              // rows per block in norms_spart

// ---------------- workspace layout (bytes) ----------------
// sorted_pts4 : f32x4 [B]      @ 0        (131072)
// sorted_idx  : i32  [B]       @ 131072   (32768)
// startg      : i32  [NC+1]    @ 163840   (16388, reserve 32768)
// invn        : f64  [TOT]     @ 196608   (131072)
// S_part      : f64  [128*256] @ 327680   (262144)
// S           : f64  [256]     @ 589824   (2048)
// comb        : f64  [TOT]     @ 591872   (131072)
// skey        : f64  [TOT]     @ 722944   (131072)
// sidx        : i32  [TOT]     @ 854016   (65536)
// rank        : i32  [TOT]     @ 919552   (65536)
// total ~0.99 MB

__device__ __forceinline__ int clamp_cell(float x) {
    int c = (int)(x * (float)GS);
    if (c < 0) c = 0;
    if (c > GS - 1) c = GS - 1;
    return c;
}

// G: fused grid build — zero + histogram + scan + scatter in ONE single-block
// kernel (1024 threads, LDS hist, shfl_up scan). Writes start[] (with sentinel
// start[NC]=B) and the cell-sorted point/idx arrays. Scatter order within a
// cell is atomics-nondeterministic, but the downstream kNN selection is
// (d, idx)-lexicographic => order-invariant => deterministic output.
__global__ void grid_build(const float* __restrict__ ref,
                           float4* __restrict__ sorted_pts4, int* __restrict__ sorted_idx,
                           int* __restrict__ startg) {
    __shared__ int cnt_s[NC];   // counts -> cursor
    __shared__ int wtot[16];
    int tid = threadIdx.x, lane = tid & 63, wv = tid >> 6;
    for (int c = tid; c < NC; c += 1024) cnt_s[c] = 0;
    float px[8], py[8], pz[8]; int cel[8];
    #pragma unroll
    for (int k = 0; k < 8; ++k) {
        int i = k * 1024 + tid;
        px[k] = ref[i * 3 + 0]; py[k] = ref[i * 3 + 1]; pz[k] = ref[i * 3 + 2];
        cel[k] = (clamp_cell(pz[k]) * GS + clamp_cell(py[k])) * GS + clamp_cell(px[k]);
    }
    __syncthreads();
    #pragma unroll
    for (int k = 0; k < 8; ++k) atomicAdd(&cnt_s[cel[k]], 1);
    __syncthreads();
    // scan: 4 consecutive cells per thread
    int n0 = cnt_s[tid * 4 + 0], n1 = cnt_s[tid * 4 + 1];
    int n2 = cnt_s[tid * 4 + 2], n3 = cnt_s[tid * 4 + 3];
    int s = n0 + n1 + n2 + n3;
    int incl = s;
    for (int off = 1; off < 64; off <<= 1) {
        int u = __shfl_up(incl, off, 64);
        if (lane >= off) incl += u;
    }
    if (lane == 63) wtot[wv] = incl;
    int excl = incl - s;
    __syncthreads();
    if (tid == 0) {
        int acc = 0;
        for (int w = 0; w < 16; ++w) { int t = wtot[w]; wtot[w] = acc; acc += t; }
    }
    __syncthreads();
    int base = wtot[wv] + excl;
    int st0 = base, st1 = base + n0, st2 = st1 + n1, st3 = st2 + n2;
    startg[tid * 4 + 0] = st0; startg[tid * 4 + 1] = st1;
    startg[tid * 4 + 2] = st2; startg[tid * 4 + 3] = st3;
    cnt_s[tid * 4 + 0] = st0; cnt_s[tid * 4 + 1] = st1;   // cursor init (own cells only)
    cnt_s[tid * 4 + 2] = st2; cnt_s[tid * 4 + 3] = st3;
    if (tid == 0) startg[NC] = B;
    __syncthreads();
    #pragma unroll
    for (int k = 0; k < 8; ++k) {
        float sq = __fadd_rn(__fadd_rn(__fmul_rn(px[k], px[k]), __fmul_rn(py[k], py[k])),
                             __fmul_rn(pz[k], pz[k]));   // ref-exact sq
        int pos = atomicAdd(&cnt_s[cel[k]], 1);
        sorted_pts4[pos] = make_float4(px[k], py[k], pz[k], sq);
        sorted_idx[pos]  = k * 1024 + tid;
    }
}

// G4: wave-per-query grid kNN (verified rounds 5/6). Exact f32 reference
// arithmetic, lexicographic (d, idx) selection, ring-stop margin. Cell spans
// now come from start[] + sentinel (start[c+1] == end of cell c).
__global__ void knn_grid_wave(const float4* __restrict__ sorted_pts4,
                              const int* __restrict__ sorted_idx,
                              const int* __restrict__ start,
                              float* __restrict__ out_closest) {
    int wave = threadIdx.x >> 6;
    int lane = threadIdx.x & 63;
    int k = blockIdx.x * 4 + wave;
    float4 q = sorted_pts4[k];
    int i = sorted_idx[k];
    int cx = clamp_cell(q.x), cy = clamp_cell(q.y), cz = clamp_cell(q.z);
    const float h = 1.0f / (float)GS, eps = 1e-3f;
    float w0 = INFINITY, w1 = INFINITY, w2 = INFINITY;
    int   wi0 = INT_MAX, wi1 = INT_MAX, wi2 = INT_MAX;
    int R = 0;
    while (true) {
        ++R;
        float b0 = INFINITY, b1 = INFINITY, b2 = INFINITY;
        int   i0 = INT_MAX, i1 = INT_MAX, i2 = INT_MAX;
        int xlo = max(cx - R, 0), xhi = min(cx + R, GS - 1);
        int ylo = max(cy - R, 0), yhi = min(cy + R, GS - 1);
        int zlo = max(cz - R, 0), zhi = min(cz + R, GS - 1);
        int ny = yhi - ylo + 1;
        int rows = ny * (zhi - zlo + 1);
        for (int r = lane; r < rows; r += 64) {
            int z = zlo + r / ny;
            int y = ylo + r % ny;
            int crow = (z * GS + y) * GS;
            int s = start[crow + xlo];
            int e = start[crow + xhi + 1];
            for (int t = s; t < e; ++t) {
                int j = sorted_idx[t];
                if (j == i) continue;
                float4 p = sorted_pts4[t];
                float dot = __fmaf_rn(q.z, p.z, __fmaf_rn(q.y, p.y, __fmul_rn(q.x, p.x)));
                float d2  = __fsub_rn(__fadd_rn(q.w, p.w), __fmul_rn(2.0f, dot));
                float d   = __fsqrt_rn(fmaxf(d2, 0.0f));
                bool lt2 = (d < b2) || (d == b2 && j < i2);
                if (lt2) {
                    bool lt1 = (d < b1) || (d == b1 && j < i1);
                    if (lt1) {
                        b2 = b1; i2 = i1;
                        bool lt0 = (d < b0) || (d == b0 && j < i0);
                        if (lt0) { b1 = b0; i1 = i0; b0 = d; i0 = j; }
                        else     { b1 = d; i1 = j; }
                    } else { b2 = d; i2 = j; }
                }
            }
        }
        #pragma unroll
        for (int s = 0; s < 3; ++s) {
            float d = b0; int ix = i0;
            for (int off = 32; off; off >>= 1) {
                float od = __shfl_xor(d, off, 64);
                int   oi = __shfl_xor(ix, off, 64);
                if (od < d || (od == d && oi < ix)) { d = od; ix = oi; }
            }
            if (s == 0) { w0 = d; wi0 = ix; }
            else if (s == 1) { w1 = d; wi1 = ix; }
            else { w2 = d; wi2 = ix; }
            if (i0 == ix) { b0 = b1; i0 = i1; b1 = b2; i1 = i2; b2 = INFINITY; i2 = INT_MAX; }
        }
        bool covers = (xlo == 0 && ylo == 0 && zlo == 0 &&
                       xhi == GS - 1 && yhi == GS - 1 && zhi == GS - 1);
        if (covers) break;
        if (wi2 != INT_MAX && w2 < (float)R * h - eps) break;
    }
    if (lane == 0) {
        out_closest[i * 3 + 0] = (float)wi0;
        out_closest[i * 3 + 1] = (float)wi1;
        out_closest[i * 3 + 2] = (float)wi2;
    }
}

// K3+K4 fused: per-row 1/norm AND per-block partial S in one 16 MB pass.
__global__ void norms_spart(const float* __restrict__ mem_tokens,
                            const float* __restrict__ new_tokens,
                            double* __restrict__ invn, double* __restrict__ S_part) {
    __shared__ double sacc[4][256];
    int wave = threadIdx.x >> 6;
    int lane = threadIdx.x & 63;
    int rbase = blockIdx.x * RPB;
    double a0 = 0.0, a1 = 0.0, a2 = 0.0, a3 = 0.0;
    for (int k = wave; k < RPB; k += 4) {
        int r = rbase + k;
        const float* row = (r < B) ? (mem_tokens + (size_t)r * D) : (new_tokens + (size_t)(r - B) * D);
        float4 v = *(const float4*)(row + lane * 4);
        double s = (double)v.x * (double)v.x + (double)v.y * (double)v.y +
                   (double)v.z * (double)v.z + (double)v.w * (double)v.w;
        for (int off = 32; off; off >>= 1) s += __shfl_xor(s, off, 64);
        double n = sqrt(s);
        if (n < 1e-12) n = 1e-12;
        double inv = 1.0 / n;
        if (lane == 0) invn[r] = inv;
        a0 += (double)v.x * inv; a1 += (double)v.y * inv;
        a2 += (double)v.z * inv; a3 += (double)v.w * inv;
    }
    sacc[wave][lane * 4 + 0] = a0;
    sacc[wave][lane * 4 + 1] = a1;
    sacc[wave][lane * 4 + 2] = a2;
    sacc[wave][lane * 4 + 3] = a3;
    __syncthreads();
    int d = threadIdx.x;
    S_part[blockIdx.x * 256 + d] = sacc[0][d] + sacc[1][d] + sacc[2][d] + sacc[3][d];
}

// K5: reduce partials -> S[256]
__global__ void s_reduce(const double* __restrict__ S_part, double* __restrict__ S) {
    int d = threadIdx.x;
    double s = 0.0;
    for (int b = 0; b < TOT / RPB; ++b) s += S_part[b * 256 + d];
    S[d] = s;
}

// K6: combined[i] = age_i - invn_i * (t_i . S). One wave per row.
__global__ void combined_kernel(const float* __restrict__ mem_tokens, const float* __restrict__ new_tokens,
                                const float* __restrict__ mem_ages,
                                const double* __restrict__ invn, const double* __restrict__ S,
                                double* __restrict__ comb) {
    int wave = threadIdx.x >> 6;
    int lane = threadIdx.x & 63;
    int r = blockIdx.x * 4 + wave;
    const float* row = (r < B) ? (mem_tokens + (size_t)r * D) : (new_tokens + (size_t)(r - B) * D);
    float4 v = *(const float4*)(row + lane * 4);
    const double* Sp = S + lane * 4;
    double s = (double)v.x * Sp[0] + (double)v.y * Sp[1] +
               (double)v.z * Sp[2] + (double)v.w * Sp[3];
    for (int off = 32; off; off >>= 1) s += __shfl_down(s, off, 64);
    if (lane == 0) {
        double age = (r < B) ? (double)mem_ages[r] + 1.0 : 0.0;
        comb[r] = age - s * invn[r];
    }
}

// K7: single-block bucket rank. rank[i] = #{j : (cj,j) <lex (ci,i)} computed as
// (elements in strictly-lower value buckets) + (exact lex count within bucket).
// Bucketing by monotone f64 map => lower bucket implies strictly smaller value;
// equal values share a bucket => semantics identical to full O(N^2) count.
// Atomics (hist counts, cursors) are order-independent => deterministic ranks.
__global__ void bucket_rank(const double* __restrict__ comb,
                            double* __restrict__ skey, int* __restrict__ sidx,
                            int* __restrict__ rank) {
    __shared__ int cnt_s[NB];      // counts -> cursor -> end
    __shared__ int start_s[NB];
    __shared__ int wtot[16];
    __shared__ double wred[32];
    __shared__ double mm[2];
    int tid = threadIdx.x, lane = tid & 63, wv = tid >> 6;
    double v[16];
    double vmin = 1e300, vmax = -1e300;
    #pragma unroll
    for (int k = 0; k < 16; ++k) {
        v[k] = comb[k * 1024 + tid];
        vmin = fmin(vmin, v[k]); vmax = fmax(vmax, v[k]);
    }
    for (int off = 32; off; off >>= 1) {
        vmin = fmin(vmin, __shfl_xor(vmin, off, 64));
        vmax = fmax(vmax, __shfl_xor(vmax, off, 64));
    }
    if (lane == 0) { wred[wv] = vmin; wred[16 + wv] = vmax; }
    for (int c = tid; c < NB; c += 1024) cnt_s[c] = 0;
    __syncthreads();
    if (tid == 0) {
        double a = wred[0], b = wred[16];
        for (int w = 1; w < 16; ++w) { a = fmin(a, wred[w]); b = fmax(b, wred[16 + w]); }
        mm[0] = a; mm[1] = b;
    }
    __syncthreads();
    double bmin = mm[0], bmax = mm[1];
    double scale = (bmax > bmin) ? (double)NB / (bmax - bmin) : 0.0;
    int bk[16];
    #pragma unroll
    for (int k = 0; k < 16; ++k) {
        int b = (int)((v[k] - bmin) * scale);
        if (b > NB - 1) b = NB - 1;
        bk[k] = b;
        atomicAdd(&cnt_s[b], 1);
    }
    __syncthreads();
    // scan: 4 consecutive buckets per thread
    int n0 = cnt_s[tid * 4 + 0], n1 = cnt_s[tid * 4 + 1];
    int n2 = cnt_s[tid * 4 + 2], n3 = cnt_s[tid * 4 + 3];
    int s = n0 + n1 + n2 + n3;
    int incl = s;
    for (int off = 1; off < 64; off <<= 1) {
        int u = __shfl_up(incl, off, 64);
        if (lane >= off) incl += u;
    }
    if (lane == 63) wtot[wv] = incl;
    int excl = incl - s;
    __syncthreads();
    if (tid == 0) {
        int acc = 0;
        for (int w = 0; w < 16; ++w) { int t = wtot[w]; wtot[w] = acc; acc += t; }
    }
    __syncthreads();
    int base = wtot[wv] + excl;
    int st0 = base, st1 = base + n0, st2 = st1 + n1, st3 = st2 + n2;
    start_s[tid * 4 + 0] = st0; start_s[tid * 4 + 1] = st1;
    start_s[tid * 4 + 2] = st2; start_s[tid * 4 + 3] = st3;
    cnt_s[tid * 4 + 0] = st0; cnt_s[tid * 4 + 1] = st1;
    cnt_s[tid * 4 + 2] = st2; cnt_s[tid * 4 + 3] = st3;
    __syncthreads();
    #pragma unroll
    for (int k = 0; k < 16; ++k) {
        int pos = atomicAdd(&cnt_s[bk[k]], 1);
        skey[pos] = v[k];
        sidx[pos] = k * 1024 + tid;
    }
    __syncthreads();   // block-wide fence: global skey/sidx visible (single CU)
    for (int p = tid; p < TOT; p += 1024) {
        double key = skey[p]; int idx = sidx[p];
        int b = (int)((key - bmin) * scale);
        if (b > NB - 1) b = NB - 1;
        int s0 = start_s[b], e0 = cnt_s[b];   // cnt_s now holds bucket end
        int r = s0;
        for (int q = s0; q < e0; ++q) {
            double kq = skey[q]; int iq = sidx[q];
            r += (kq < key) || (kq == key && iq < idx);
        }
        rank[idx] = r;
    }
}

// K8: scatter kept rows to out[rank[i]], float4-vectorized. One block per source row.
__global__ void gather(const float* __restrict__ mem_keys, const float* __restrict__ mem_tokens,
                       const float* __restrict__ new_tokens, const float* __restrict__ mem_ages,
                       const int* __restrict__ rank,
                       float* __restrict__ out_keys, float* __restrict__ out_tokens,
                       float* __restrict__ out_ages) {
    int r  = blockIdx.x;
    int rk = rank[r];
    if (rk >= B) return;
    int t = threadIdx.x;
    float4* ot = (float4*)(out_tokens + (size_t)rk * D);
    float4* ok = (float4*)(out_keys + (size_t)rk * 3 * D);
    if (r < B) {
        if (t < 64) {
            const float4* st = (const float4*)(mem_tokens + (size_t)r * D);
            ot[t] = st[t];
        } else {
            const float4* sk = (const float4*)(mem_keys + (size_t)r * 3 * D);
            ok[t - 64] = sk[t - 64];
        }
        if (t == 0) out_ages[rk] = mem_ages[r] + 1.0f;
    } else {
        const float4* nt = (const float4*)(new_tokens + (size_t)(r - B) * D);
        float4 v = nt[t & 63];
        if (t < 64) ot[t] = v;
        else        ok[t - 64] = v;
        if (t == 0) out_ages[rk] = 0.0f;
    }
}

extern "C" void kernel_launch(void* const* d_in, const int* in_sizes, int n_in,
                              void* d_out, int out_size, void* d_ws, size_t ws_size,
                              hipStream_t stream) {
    const float* new_tokens = (const float*)d_in[0];  // [8192,256]
    const float* ref_pts    = (const float*)d_in[1];  // [8192,3]
    const float* mem_keys   = (const float*)d_in[2];  // [8192,3,256]
    const float* mem_tokens = (const float*)d_in[3];  // [8192,256]
    const float* mem_ages   = (const float*)d_in[4];  // [8192]

    char* ws = (char*)d_ws;
    float4* sorted_pts4 = (float4*)(ws + 0);
    int*    sorted_idx  = (int*)   (ws + 131072);
    int*    startg      = (int*)   (ws + 163840);
    double* invn        = (double*)(ws + 196608);
    double* S_part      = (double*)(ws + 327680);
    double* S           = (double*)(ws + 589824);
    double* comb        = (double*)(ws + 591872);
    double* skey        = (double*)(ws + 722944);
    int*    sidx        = (int*)   (ws + 854016);
    int*    rank        = (int*)   (ws + 919552);

    float* out = (float*)d_out;
    float* out_keys    = out;                       // 8192*3*256 = 6291456
    float* out_tokens  = out + 6291456;             // 8192*256   = 2097152
    float* out_ages    = out + 6291456 + 2097152;   // 8192
    float* out_closest = out_ages + 8192;           // 8192*3 (written as float)

    grid_build<<<1, 1024, 0, stream>>>(ref_pts, sorted_pts4, sorted_idx, startg);
    knn_grid_wave<<<B / 4, 256, 0, stream>>>(sorted_pts4, sorted_idx, startg, out_closest);

    norms_spart<<<TOT / RPB, 256, 0, stream>>>(mem_tokens, new_tokens, invn, S_part);
    s_reduce<<<1, 256, 0, stream>>>(S_part, S);
    combined_kernel<<<TOT / 4, 256, 0, stream>>>(mem_tokens, new_tokens, mem_ages, invn, S, comb);
    bucket_rank<<<1, 1024, 0, stream>>>(comb, skey, sidx, rank);
    gather<<<TOT, 256, 0, stream>>>(mem_keys, mem_tokens, new_tokens, mem_ages, rank,
                                    out_keys, out_tokens, out_ages);
}

// Round 8
// 135.803 us; speedup vs baseline: 1.4200x; 1.4200x over previous
//
#include <hip/hip_runtime.h>
#include <climits>

#define B    8192
#define D    256
#define TOT  16384
#define GS   16
#define NC   (GS * GS * GS)   // 4096 grid cells
#define NCH  32               // rank j-chunks
#define JCW  (TOT / NCH)      // 512
#define RPB  128              // rows per block in norms part

// ---------------- workspace layout (bytes) ----------------
// sorted_pts4 : f32x4 [B]      @ 0        (131072)
// sorted_idx  : i32  [B]       @ 131072   (32768)
// startg      : i32  [NC+1]    @ 163840   (reserve 32768)
// invn        : f64  [TOT]     @ 196608   (131072)
// S_part      : f64  [128*256] @ 327680   (262144)
// S           : f64  [256]     @ 589824   (2048)
// comb        : f64  [TOT]     @ 591872   (131072)
// partial     : i32  [NCH*TOT] @ 722944   (2097152)
// total ~2.82 MB

__device__ __forceinline__ int clamp_cell(float x) {
    int c = (int)(x * (float)GS);
    if (c < 0) c = 0;
    if (c > GS - 1) c = GS - 1;
    return c;
}

// Kernel A: blocks 0..127 -> fused row-norms + partial-S (verified r6);
//           block 128    -> grid build (zero+hist+scan+scatter, 256-thr).
__global__ void norms_grid(const float* __restrict__ mem_tokens,
                           const float* __restrict__ new_tokens,
                           const float* __restrict__ ref,
                           double* __restrict__ invn, double* __restrict__ S_part,
                           float4* __restrict__ sorted_pts4, int* __restrict__ sorted_idx,
                           int* __restrict__ startg) {
    __shared__ double sacc[4][256];          // norms branch (8 KB)
    __shared__ int cnt_s[NC];                // grid branch (16 KB)
    __shared__ int part[256];
    if (blockIdx.x < 128) {
        int wave = threadIdx.x >> 6;
        int lane = threadIdx.x & 63;
        int rbase = blockIdx.x * RPB;
        double a0 = 0.0, a1 = 0.0, a2 = 0.0, a3 = 0.0;
        for (int k = wave; k < RPB; k += 4) {
            int r = rbase + k;
            const float* row = (r < B) ? (mem_tokens + (size_t)r * D) : (new_tokens + (size_t)(r - B) * D);
            float4 v = *(const float4*)(row + lane * 4);
            double s = (double)v.x * (double)v.x + (double)v.y * (double)v.y +
                       (double)v.z * (double)v.z + (double)v.w * (double)v.w;
            for (int off = 32; off; off >>= 1) s += __shfl_xor(s, off, 64);
            double n = sqrt(s);
            if (n < 1e-12) n = 1e-12;
            double inv = 1.0 / n;
            if (lane == 0) invn[r] = inv;
            a0 += (double)v.x * inv; a1 += (double)v.y * inv;
            a2 += (double)v.z * inv; a3 += (double)v.w * inv;
        }
        sacc[wave][lane * 4 + 0] = a0;
        sacc[wave][lane * 4 + 1] = a1;
        sacc[wave][lane * 4 + 2] = a2;
        sacc[wave][lane * 4 + 3] = a3;
        __syncthreads();
        int d = threadIdx.x;
        S_part[blockIdx.x * 256 + d] = sacc[0][d] + sacc[1][d] + sacc[2][d] + sacc[3][d];
    } else {
        int tid = threadIdx.x;
        for (int c = tid; c < NC; c += 256) cnt_s[c] = 0;
        __syncthreads();
        for (int k = 0; k < 32; ++k) {
            int i = k * 256 + tid;
            int cx = clamp_cell(ref[i * 3 + 0]);
            int cy = clamp_cell(ref[i * 3 + 1]);
            int cz = clamp_cell(ref[i * 3 + 2]);
            atomicAdd(&cnt_s[(cz * GS + cy) * GS + cx], 1);
        }
        __syncthreads();
        int s = 0;
        for (int k = 0; k < 16; ++k) s += cnt_s[tid * 16 + k];
        part[tid] = s;
        __syncthreads();
        if (tid == 0) {
            int acc = 0;
            for (int q = 0; q < 256; ++q) { int v = part[q]; part[q] = acc; acc += v; }
        }
        __syncthreads();
        int base = part[tid];
        for (int k = 0; k < 16; ++k) {
            int c = tid * 16 + k;
            int v = cnt_s[c];
            startg[c] = base;
            cnt_s[c] = base;                 // cursor init
            base += v;
        }
        if (tid == 0) startg[NC] = B;
        __syncthreads();
        for (int k = 0; k < 32; ++k) {
            int i = k * 256 + tid;
            float x = ref[i * 3 + 0], y = ref[i * 3 + 1], z = ref[i * 3 + 2];
            int c = (clamp_cell(z) * GS + clamp_cell(y)) * GS + clamp_cell(x);
            float sq = __fadd_rn(__fadd_rn(__fmul_rn(x, x), __fmul_rn(y, y)), __fmul_rn(z, z));
            int pos = atomicAdd(&cnt_s[c], 1);
            sorted_pts4[pos] = make_float4(x, y, z, sq);
            sorted_idx[pos]  = i;
        }
    }
}

// Kernel B: blocks 0..2047 -> wave-per-query grid kNN (verified r5/6);
//           block 2048    -> S_part reduce -> S.
__global__ void knn_sreduce(const float4* __restrict__ sorted_pts4,
                            const int* __restrict__ sorted_idx,
                            const int* __restrict__ start,
                            float* __restrict__ out_closest,
                            const double* __restrict__ S_part, double* __restrict__ S) {
    if (blockIdx.x == 2048) {
        int d = threadIdx.x;
        double s = 0.0;
        for (int b = 0; b < TOT / RPB; ++b) s += S_part[b * 256 + d];
        S[d] = s;
        return;
    }
    int wave = threadIdx.x >> 6;
    int lane = threadIdx.x & 63;
    int k = blockIdx.x * 4 + wave;
    float4 q = sorted_pts4[k];
    int i = sorted_idx[k];
    int cx = clamp_cell(q.x), cy = clamp_cell(q.y), cz = clamp_cell(q.z);
    const float h = 1.0f / (float)GS, eps = 1e-3f;
    float w0 = INFINITY, w1 = INFINITY, w2 = INFINITY;
    int   wi0 = INT_MAX, wi1 = INT_MAX, wi2 = INT_MAX;
    int R = 0;
    while (true) {
        ++R;
        float b0 = INFINITY, b1 = INFINITY, b2 = INFINITY;
        int   i0 = INT_MAX, i1 = INT_MAX, i2 = INT_MAX;
        int xlo = max(cx - R, 0), xhi = min(cx + R, GS - 1);
        int ylo = max(cy - R, 0), yhi = min(cy + R, GS - 1);
        int zlo = max(cz - R, 0), zhi = min(cz + R, GS - 1);
        int ny = yhi - ylo + 1;
        int rows = ny * (zhi - zlo + 1);
        for (int r = lane; r < rows; r += 64) {
            int z = zlo + r / ny;
            int y = ylo + r % ny;
            int crow = (z * GS + y) * GS;
            int s = start[crow + xlo];
            int e = start[crow + xhi + 1];
            for (int t = s; t < e; ++t) {
                int j = sorted_idx[t];
                if (j == i) continue;
                float4 p = sorted_pts4[t];
                float dot = __fmaf_rn(q.z, p.z, __fmaf_rn(q.y, p.y, __fmul_rn(q.x, p.x)));
                float d2  = __fsub_rn(__fadd_rn(q.w, p.w), __fmul_rn(2.0f, dot));
                float d   = __fsqrt_rn(fmaxf(d2, 0.0f));
                bool lt2 = (d < b2) || (d == b2 && j < i2);
                if (lt2) {
                    bool lt1 = (d < b1) || (d == b1 && j < i1);
                    if (lt1) {
                        b2 = b1; i2 = i1;
                        bool lt0 = (d < b0) || (d == b0 && j < i0);
                        if (lt0) { b1 = b0; i1 = i0; b0 = d; i0 = j; }
                        else     { b1 = d; i1 = j; }
                    } else { b2 = d; i2 = j; }
                }
            }
        }
        #pragma unroll
        for (int s = 0; s < 3; ++s) {
            float d = b0; int ix = i0;
            for (int off = 32; off; off >>= 1) {
                float od = __shfl_xor(d, off, 64);
                int   oi = __shfl_xor(ix, off, 64);
                if (od < d || (od == d && oi < ix)) { d = od; ix = oi; }
            }
            if (s == 0) { w0 = d; wi0 = ix; }
            else if (s == 1) { w1 = d; wi1 = ix; }
            else { w2 = d; wi2 = ix; }
            if (i0 == ix) { b0 = b1; i0 = i1; b1 = b2; i1 = i2; b2 = INFINITY; i2 = INT_MAX; }
        }
        bool covers = (xlo == 0 && ylo == 0 && zlo == 0 &&
                       xhi == GS - 1 && yhi == GS - 1 && zhi == GS - 1);
        if (covers) break;
        if (wi2 != INT_MAX && w2 < (float)R * h - eps) break;
    }
    if (lane == 0) {
        out_closest[i * 3 + 0] = (float)wi0;
        out_closest[i * 3 + 1] = (float)wi1;
        out_closest[i * 3 + 2] = (float)wi2;
    }
}

// Kernel C: combined[i] = age_i - invn_i * (t_i . S). One wave per row.
__global__ void combined_kernel(const float* __restrict__ mem_tokens, const float* __restrict__ new_tokens,
                                const float* __restrict__ mem_ages,
                                const double* __restrict__ invn, const double* __restrict__ S,
                                double* __restrict__ comb) {
    int wave = threadIdx.x >> 6;
    int lane = threadIdx.x & 63;
    int r = blockIdx.x * 4 + wave;
    const float* row = (r < B) ? (mem_tokens + (size_t)r * D) : (new_tokens + (size_t)(r - B) * D);
    float4 v = *(const float4*)(row + lane * 4);
    const double* Sp = S + lane * 4;
    double s = (double)v.x * Sp[0] + (double)v.y * Sp[1] +
               (double)v.z * Sp[2] + (double)v.w * Sp[3];
    for (int off = 32; off; off >>= 1) s += __shfl_down(s, off, 64);
    if (lane == 0) {
        double age = (r < B) ? (double)mem_ages[r] + 1.0 : 0.0;
        comb[r] = age - s * invn[r];
    }
}

// Kernel D: stable rank count (verified r6), NO atomics. 4 consecutive i per
// thread; per-chunk counts -> partial[chunk][i] (int4 store). Split-loop keeps
// the exact lexicographic order; straddle window (<=4 iters) does tie-break.
__global__ void rank_count(const double* __restrict__ comb, int* __restrict__ partial) {
    __shared__ double cl[JCW];
    int tid  = threadIdx.x;
    int base = (blockIdx.x * 256 + tid) * 4;
    int j0   = blockIdx.y * JCW;
    for (int t = tid; t < JCW; t += 256) cl[t] = comb[j0 + t];
    __syncthreads();
    double c0 = comb[base + 0], c1 = comb[base + 1];
    double c2 = comb[base + 2], c3 = comb[base + 3];
    int n0 = 0, n1 = 0, n2 = 0, n3 = 0;
    int lo = base - j0;       if (lo < 0) lo = 0; if (lo > JCW) lo = JCW;
    int hi = base + 4 - j0;   if (hi < 0) hi = 0; if (hi > JCW) hi = JCW;
    #pragma unroll 8
    for (int t = 0; t < lo; ++t) {
        double cj = cl[t];
        n0 += (cj <= c0); n1 += (cj <= c1); n2 += (cj <= c2); n3 += (cj <= c3);
    }
    for (int t = lo; t < hi; ++t) {
        double cj = cl[t];
        int j = j0 + t;
        n0 += (cj < c0) || (cj == c0 && j < base + 0);
        n1 += (cj < c1) || (cj == c1 && j < base + 1);
        n2 += (cj < c2) || (cj == c2 && j < base + 2);
        n3 += (cj < c3) || (cj == c3 && j < base + 3);
    }
    #pragma unroll 8
    for (int t = hi; t < JCW; ++t) {
        double cj = cl[t];
        n0 += (cj < c0); n1 += (cj < c1); n2 += (cj < c2); n3 += (cj < c3);
    }
    *(int4*)&partial[blockIdx.y * TOT + base] = make_int4(n0, n1, n2, n3);
}

// Kernel E: gather with inline rank reduction (sums 32 per-chunk partials,
// uniform per block -> scalar loads). float4-vectorized copies.
__global__ void gather(const float* __restrict__ mem_keys, const float* __restrict__ mem_tokens,
                       const float* __restrict__ new_tokens, const float* __restrict__ mem_ages,
                       const int* __restrict__ partial,
                       float* __restrict__ out_keys, float* __restrict__ out_tokens,
                       float* __restrict__ out_ages) {
    int r = blockIdx.x;
    int rk = 0;
    #pragma unroll
    for (int ch = 0; ch < NCH; ++ch) rk += partial[ch * TOT + r];
    if (rk >= B) return;
    int t = threadIdx.x;
    float4* ot = (float4*)(out_tokens + (size_t)rk * D);
    float4* ok = (float4*)(out_keys + (size_t)rk * 3 * D);
    if (r < B) {
        if (t < 64) {
            const float4* st = (const float4*)(mem_tokens + (size_t)r * D);
            ot[t] = st[t];
        } else {
            const float4* sk = (const float4*)(mem_keys + (size_t)r * 3 * D);
            ok[t - 64] = sk[t - 64];
        }
        if (t == 0) out_ages[rk] = mem_ages[r] + 1.0f;
    } else {
        const float4* nt = (const float4*)(new_tokens + (size_t)(r - B) * D);
        float4 v = nt[t & 63];
        if (t < 64) ot[t] = v;
        else        ok[t - 64] = v;
        if (t == 0) out_ages[rk] = 0.0f;
    }
}

extern "C" void kernel_launch(void* const* d_in, const int* in_sizes, int n_in,
                              void* d_out, int out_size, void* d_ws, size_t ws_size,
                              hipStream_t stream) {
    const float* new_tokens = (const float*)d_in[0];  // [8192,256]
    const float* ref_pts    = (const float*)d_in[1];  // [8192,3]
    const float* mem_keys   = (const float*)d_in[2];  // [8192,3,256]
    const float* mem_tokens = (const float*)d_in[3];  // [8192,256]
    const float* mem_ages   = (const float*)d_in[4];  // [8192]

    char* ws = (char*)d_ws;
    float4* sorted_pts4 = (float4*)(ws + 0);
    int*    sorted_idx  = (int*)   (ws + 131072);
    int*    startg      = (int*)   (ws + 163840);
    double* invn        = (double*)(ws + 196608);
    double* S_part      = (double*)(ws + 327680);
    double* S           = (double*)(ws + 589824);
    double* comb        = (double*)(ws + 591872);
    int*    partial     = (int*)   (ws + 722944);

    float* out = (float*)d_out;
    float* out_keys    = out;                       // 8192*3*256 = 6291456
    float* out_tokens  = out + 6291456;             // 8192*256   = 2097152
    float* out_ages    = out + 6291456 + 2097152;   // 8192
    float* out_closest = out_ages + 8192;           // 8192*3 (written as float)

    norms_grid<<<129, 256, 0, stream>>>(mem_tokens, new_tokens, ref_pts,
                                        invn, S_part, sorted_pts4, sorted_idx, startg);
    knn_sreduce<<<2049, 256, 0, stream>>>(sorted_pts4, sorted_idx, startg,
                                          out_closest, S_part, S);
    combined_kernel<<<TOT / 4, 256, 0, stream>>>(mem_tokens, new_tokens, mem_ages, invn, S, comb);
    rank_count<<<dim3(TOT / (256 * 4), NCH), 256, 0, stream>>>(comb, partial);
    gather<<<TOT, 256, 0, stream>>>(mem_keys, mem_tokens, new_tokens, mem_ages, partial,
                                    out_keys, out_tokens, out_ages);
}

// Round 9
// 92.813 us; speedup vs baseline: 2.0777x; 1.4632x over previous
//
#include <hip/hip_runtime.h>
#include <climits>

#define B    8192
#define D    256
#define TOT  16384
#define GS   16
#define NC   (GS * GS * GS)   // 4096 grid cells
#define NCH  32               // rank j-chunks
#define JCW  (TOT / NCH)      // 512
#define RPB  128              // rows per block in norms part

// ---------------- workspace layout (bytes) ----------------
// sorted_pts4 : f32x4 [B]      @ 0        (131072)
// sorted_idx  : i32  [B]       @ 131072   (32768)
// startg      : i32  [NC+1]    @ 163840   (reserve 32768)
// invn        : f64  [TOT]     @ 196608   (131072)
// S_part      : f64  [128*256] @ 327680   (262144)
// S           : f64  [256]     @ 589824   (2048)
// comb        : f64  [TOT]     @ 591872   (131072)
// partial     : i32  [NCH*TOT] @ 722944   (2097152)
// total ~2.82 MB

__device__ __forceinline__ int clamp_cell(float x) {
    int c = (int)(x * (float)GS);
    if (c < 0) c = 0;
    if (c > GS - 1) c = GS - 1;
    return c;
}

// Kernel A: blocks 0..127 -> fused row-norms + partial-S (verified r6);
//           block 128    -> grid build (zero+hist+scan+scatter, 256-thr).
__global__ void norms_grid(const float* __restrict__ mem_tokens,
                           const float* __restrict__ new_tokens,
                           const float* __restrict__ ref,
                           double* __restrict__ invn, double* __restrict__ S_part,
                           float4* __restrict__ sorted_pts4, int* __restrict__ sorted_idx,
                           int* __restrict__ startg) {
    __shared__ double sacc[4][256];          // norms branch (8 KB)
    __shared__ int cnt_s[NC];                // grid branch (16 KB)
    __shared__ int part[256];
    if (blockIdx.x < 128) {
        int wave = threadIdx.x >> 6;
        int lane = threadIdx.x & 63;
        int rbase = blockIdx.x * RPB;
        double a0 = 0.0, a1 = 0.0, a2 = 0.0, a3 = 0.0;
        for (int k = wave; k < RPB; k += 4) {
            int r = rbase + k;
            const float* row = (r < B) ? (mem_tokens + (size_t)r * D) : (new_tokens + (size_t)(r - B) * D);
            float4 v = *(const float4*)(row + lane * 4);
            double s = (double)v.x * (double)v.x + (double)v.y * (double)v.y +
                       (double)v.z * (double)v.z + (double)v.w * (double)v.w;
            for (int off = 32; off; off >>= 1) s += __shfl_xor(s, off, 64);
            double n = sqrt(s);
            if (n < 1e-12) n = 1e-12;
            double inv = 1.0 / n;
            if (lane == 0) invn[r] = inv;
            a0 += (double)v.x * inv; a1 += (double)v.y * inv;
            a2 += (double)v.z * inv; a3 += (double)v.w * inv;
        }
        sacc[wave][lane * 4 + 0] = a0;
        sacc[wave][lane * 4 + 1] = a1;
        sacc[wave][lane * 4 + 2] = a2;
        sacc[wave][lane * 4 + 3] = a3;
        __syncthreads();
        int d = threadIdx.x;
        S_part[blockIdx.x * 256 + d] = sacc[0][d] + sacc[1][d] + sacc[2][d] + sacc[3][d];
    } else {
        int tid = threadIdx.x;
        for (int c = tid; c < NC; c += 256) cnt_s[c] = 0;
        __syncthreads();
        for (int k = 0; k < 32; ++k) {
            int i = k * 256 + tid;
            int cx = clamp_cell(ref[i * 3 + 0]);
            int cy = clamp_cell(ref[i * 3 + 1]);
            int cz = clamp_cell(ref[i * 3 + 2]);
            atomicAdd(&cnt_s[(cz * GS + cy) * GS + cx], 1);
        }
        __syncthreads();
        int s = 0;
        for (int k = 0; k < 16; ++k) s += cnt_s[tid * 16 + k];
        part[tid] = s;
        __syncthreads();
        if (tid == 0) {
            int acc = 0;
            for (int q = 0; q < 256; ++q) { int v = part[q]; part[q] = acc; acc += v; }
        }
        __syncthreads();
        int base = part[tid];
        for (int k = 0; k < 16; ++k) {
            int c = tid * 16 + k;
            int v = cnt_s[c];
            startg[c] = base;
            cnt_s[c] = base;                 // cursor init
            base += v;
        }
        if (tid == 0) startg[NC] = B;
        __syncthreads();
        for (int k = 0; k < 32; ++k) {
            int i = k * 256 + tid;
            float x = ref[i * 3 + 0], y = ref[i * 3 + 1], z = ref[i * 3 + 2];
            int c = (clamp_cell(z) * GS + clamp_cell(y)) * GS + clamp_cell(x);
            float sq = __fadd_rn(__fadd_rn(__fmul_rn(x, x), __fmul_rn(y, y)), __fmul_rn(z, z));
            int pos = atomicAdd(&cnt_s[c], 1);
            sorted_pts4[pos] = make_float4(x, y, z, sq);
            sorted_idx[pos]  = i;
        }
    }
}

// Kernel B: blocks 0..2047 -> wave-per-query grid kNN (verified r5/6);
//           block 2048    -> S_part reduce -> S.
__global__ void knn_sreduce(const float4* __restrict__ sorted_pts4,
                            const int* __restrict__ sorted_idx,
                            const int* __restrict__ start,
                            float* __restrict__ out_closest,
                            const double* __restrict__ S_part, double* __restrict__ S) {
    if (blockIdx.x == 2048) {
        int d = threadIdx.x;
        double s = 0.0;
        for (int b = 0; b < TOT / RPB; ++b) s += S_part[b * 256 + d];
        S[d] = s;
        return;
    }
    int wave = threadIdx.x >> 6;
    int lane = threadIdx.x & 63;
    int k = blockIdx.x * 4 + wave;
    float4 q = sorted_pts4[k];
    int i = sorted_idx[k];
    int cx = clamp_cell(q.x), cy = clamp_cell(q.y), cz = clamp_cell(q.z);
    const float h = 1.0f / (float)GS, eps = 1e-3f;
    float w0 = INFINITY, w1 = INFINITY, w2 = INFINITY;
    int   wi0 = INT_MAX, wi1 = INT_MAX, wi2 = INT_MAX;
    int R = 0;
    while (true) {
        ++R;
        float b0 = INFINITY, b1 = INFINITY, b2 = INFINITY;
        int   i0 = INT_MAX, i1 = INT_MAX, i2 = INT_MAX;
        int xlo = max(cx - R, 0), xhi = min(cx + R, GS - 1);
        int ylo = max(cy - R, 0), yhi = min(cy + R, GS - 1);
        int zlo = max(cz - R, 0), zhi = min(cz + R, GS - 1);
        int ny = yhi - ylo + 1;
        int rows = ny * (zhi - zlo + 1);
        for (int r = lane; r < rows; r += 64) {
            int z = zlo + r / ny;
            int y = ylo + r % ny;
            int crow = (z * GS + y) * GS;
            int s = start[crow + xlo];
            int e = start[crow + xhi + 1];
            for (int t = s; t < e; ++t) {
                int j = sorted_idx[t];
                if (j == i) continue;
                float4 p = sorted_pts4[t];
                float dot = __fmaf_rn(q.z, p.z, __fmaf_rn(q.y, p.y, __fmul_rn(q.x, p.x)));
                float d2  = __fsub_rn(__fadd_rn(q.w, p.w), __fmul_rn(2.0f, dot));
                float d   = __fsqrt_rn(fmaxf(d2, 0.0f));
                bool lt2 = (d < b2) || (d == b2 && j < i2);
                if (lt2) {
                    bool lt1 = (d < b1) || (d == b1 && j < i1);
                    if (lt1) {
                        b2 = b1; i2 = i1;
                        bool lt0 = (d < b0) || (d == b0 && j < i0);
                        if (lt0) { b1 = b0; i1 = i0; b0 = d; i0 = j; }
                        else     { b1 = d; i1 = j; }
                    } else { b2 = d; i2 = j; }
                }
            }
        }
        #pragma unroll
        for (int s = 0; s < 3; ++s) {
            float d = b0; int ix = i0;
            for (int off = 32; off; off >>= 1) {
                float od = __shfl_xor(d, off, 64);
                int   oi = __shfl_xor(ix, off, 64);
                if (od < d || (od == d && oi < ix)) { d = od; ix = oi; }
            }
            if (s == 0) { w0 = d; wi0 = ix; }
            else if (s == 1) { w1 = d; wi1 = ix; }
            else { w2 = d; wi2 = ix; }
            if (i0 == ix) { b0 = b1; i0 = i1; b1 = b2; i1 = i2; b2 = INFINITY; i2 = INT_MAX; }
        }
        bool covers = (xlo == 0 && ylo == 0 && zlo == 0 &&
                       xhi == GS - 1 && yhi == GS - 1 && zhi == GS - 1);
        if (covers) break;
        if (wi2 != INT_MAX && w2 < (float)R * h - eps) break;
    }
    if (lane == 0) {
        out_closest[i * 3 + 0] = (float)wi0;
        out_closest[i * 3 + 1] = (float)wi1;
        out_closest[i * 3 + 2] = (float)wi2;
    }
}

// Kernel C: combined[i] = age_i - invn_i * (t_i . S). One wave per row.
__global__ void combined_kernel(const float* __restrict__ mem_tokens, const float* __restrict__ new_tokens,
                                const float* __restrict__ mem_ages,
                                const double* __restrict__ invn, const double* __restrict__ S,
                                double* __restrict__ comb) {
    int wave = threadIdx.x >> 6;
    int lane = threadIdx.x & 63;
    int r = blockIdx.x * 4 + wave;
    const float* row = (r < B) ? (mem_tokens + (size_t)r * D) : (new_tokens + (size_t)(r - B) * D);
    float4 v = *(const float4*)(row + lane * 4);
    const double* Sp = S + lane * 4;
    double s = (double)v.x * Sp[0] + (double)v.y * Sp[1] +
               (double)v.z * Sp[2] + (double)v.w * Sp[3];
    for (int off = 32; off; off >>= 1) s += __shfl_down(s, off, 64);
    if (lane == 0) {
        double age = (r < B) ? (double)mem_ages[r] + 1.0 : 0.0;
        comb[r] = age - s * invn[r];
    }
}

// Kernel D: stable rank count (verified r6), NO atomics. 4 consecutive i per
// thread; per-chunk counts -> partial[chunk][i] (int4 store). Split-loop keeps
// the exact lexicographic order; straddle window (<=4 iters) does tie-break.
__global__ void rank_count(const double* __restrict__ comb, int* __restrict__ partial) {
    __shared__ double cl[JCW];
    int tid  = threadIdx.x;
    int base = (blockIdx.x * 256 + tid) * 4;
    int j0   = blockIdx.y * JCW;
    for (int t = tid; t < JCW; t += 256) cl[t] = comb[j0 + t];
    __syncthreads();
    double c0 = comb[base + 0], c1 = comb[base + 1];
    double c2 = comb[base + 2], c3 = comb[base + 3];
    int n0 = 0, n1 = 0, n2 = 0, n3 = 0;
    int lo = base - j0;       if (lo < 0) lo = 0; if (lo > JCW) lo = JCW;
    int hi = base + 4 - j0;   if (hi < 0) hi = 0; if (hi > JCW) hi = JCW;
    #pragma unroll 8
    for (int t = 0; t < lo; ++t) {
        double cj = cl[t];
        n0 += (cj <= c0); n1 += (cj <= c1); n2 += (cj <= c2); n3 += (cj <= c3);
    }
    for (int t = lo; t < hi; ++t) {
        double cj = cl[t];
        int j = j0 + t;
        n0 += (cj < c0) || (cj == c0 && j < base + 0);
        n1 += (cj < c1) || (cj == c1 && j < base + 1);
        n2 += (cj < c2) || (cj == c2 && j < base + 2);
        n3 += (cj < c3) || (cj == c3 && j < base + 3);
    }
    #pragma unroll 8
    for (int t = hi; t < JCW; ++t) {
        double cj = cl[t];
        n0 += (cj < c0); n1 += (cj < c1); n2 += (cj < c2); n3 += (cj < c3);
    }
    *(int4*)&partial[blockIdx.y * TOT + base] = make_int4(n0, n1, n2, n3);
}

// Kernel E: gather. Rank reduction done ONCE per block: threads 0..31 load one
// partial each (parallel, 1 latency round), LDS tree-reduce, broadcast.
// float4-vectorized copies: t<64 tokens row, t>=64 keys row.
__global__ void gather(const float* __restrict__ mem_keys, const float* __restrict__ mem_tokens,
                       const float* __restrict__ new_tokens, const float* __restrict__ mem_ages,
                       const int* __restrict__ partial,
                       float* __restrict__ out_keys, float* __restrict__ out_tokens,
                       float* __restrict__ out_ages) {
    __shared__ int psum[32];
    int r = blockIdx.x;
    int t = threadIdx.x;
    if (t < 32) psum[t] = partial[t * TOT + r];
    __syncthreads();
    if (t < 8) {
        int s = psum[t] + psum[t + 8] + psum[t + 16] + psum[t + 24];
        psum[t] = s;
    }
    __syncthreads();
    if (t == 0) {
        psum[0] = psum[0] + psum[1] + psum[2] + psum[3] +
                  psum[4] + psum[5] + psum[6] + psum[7];
    }
    __syncthreads();
    int rk = psum[0];
    if (rk >= B) return;
    float4* ot = (float4*)(out_tokens + (size_t)rk * D);
    float4* ok = (float4*)(out_keys + (size_t)rk * 3 * D);
    if (r < B) {
        if (t < 64) {
            const float4* st = (const float4*)(mem_tokens + (size_t)r * D);
            ot[t] = st[t];
        } else {
            const float4* sk = (const float4*)(mem_keys + (size_t)r * 3 * D);
            ok[t - 64] = sk[t - 64];
        }
        if (t == 0) out_ages[rk] = mem_ages[r] + 1.0f;
    } else {
        const float4* nt = (const float4*)(new_tokens + (size_t)(r - B) * D);
        float4 v = nt[t & 63];
        if (t < 64) ot[t] = v;
        else        ok[t - 64] = v;
        if (t == 0) out_ages[rk] = 0.0f;
    }
}

extern "C" void kernel_launch(void* const* d_in, const int* in_sizes, int n_in,
                              void* d_out, int out_size, void* d_ws, size_t ws_size,
                              hipStream_t stream) {
    const float* new_tokens = (const float*)d_in[0];  // [8192,256]
    const float* ref_pts    = (const float*)d_in[1];  // [8192,3]
    const float* mem_keys   = (const float*)d_in[2];  // [8192,3,256]
    const float* mem_tokens = (const float*)d_in[3];  // [8192,256]
    const float* mem_ages   = (const float*)d_in[4];  // [8192]

    char* ws = (char*)d_ws;
    float4* sorted_pts4 = (float4*)(ws + 0);
    int*    sorted_idx  = (int*)   (ws + 131072);
    int*    startg      = (int*)   (ws + 163840);
    double* invn        = (double*)(ws + 196608);
    double* S_part      = (double*)(ws + 327680);
    double* S           = (double*)(ws + 589824);
    double* comb        = (double*)(ws + 591872);
    int*    partial     = (int*)   (ws + 722944);

    float* out = (float*)d_out;
    float* out_keys    = out;                       // 8192*3*256 = 6291456
    float* out_tokens  = out + 6291456;             // 8192*256   = 2097152
    float* out_ages    = out + 6291456 + 2097152;   // 8192
    float* out_closest = out_ages + 8192;           // 8192*3 (written as float)

    norms_grid<<<129, 256, 0, stream>>>(mem_tokens, new_tokens, ref_pts,
                                        invn, S_part, sorted_pts4, sorted_idx, startg);
    knn_sreduce<<<2049, 256, 0, stream>>>(sorted_pts4, sorted_idx, startg,
                                          out_closest, S_part, S);
    combined_kernel<<<TOT / 4, 256, 0, stream>>>(mem_tokens, new_tokens, mem_ages, invn, S, comb);
    rank_count<<<dim3(TOT / (256 * 4), NCH), 256, 0, stream>>>(comb, partial);
    gather<<<TOT, 256, 0, stream>>>(mem_keys, mem_tokens, new_tokens, mem_ages, partial,
                                    out_keys, out_tokens, out_ages);
}